// Round 2
// baseline (262.810 us; speedup 1.0000x reference)
//
#include <hip/hip_runtime.h>
#include <math.h>

// YOLOv1 loss: predicts/targets (8192, 7, 7, 30) fp32 -> scalar.
// Single fused kernel: LDS-staged coalesced float4 streaming, one cell per
// thread, block partials to ws, last-arriving block does the final reduction
// (device-scope atomics for cross-XCD visibility; ws is poisoned 0xAA so all
// cross-block reads use agent-scope atomic loads).

#define S7 7
#define CCH 30
#define CELLS_PER_BLOCK 256
#define N_CELLS (8192 * S7 * S7)             // 401408
#define N_BLOCKS (N_CELLS / CELLS_PER_BLOCK) // 1568 exactly
#define EPSV 1e-6f

__device__ __forceinline__ float iou_cxcywh(float acx, float acy, float aw, float ah,
                                            float bcx, float bcy, float bw, float bh) {
    float ax1 = acx - aw * 0.5f, ax2 = acx + aw * 0.5f;
    float ay1 = acy - ah * 0.5f, ay2 = acy + ah * 0.5f;
    float bx1 = bcx - bw * 0.5f, bx2 = bcx + bw * 0.5f;
    float by1 = bcy - bh * 0.5f, by2 = bcy + bh * 0.5f;
    float iw = fmaxf(fminf(ax2, bx2) - fmaxf(ax1, bx1), 0.0f);
    float ih = fmaxf(fminf(ay2, by2) - fmaxf(ay1, by1), 0.0f);
    float inter = iw * ih;
    float area_a = (ax2 - ax1) * (ay2 - ay1);
    float area_b = (bx2 - bx1) * (by2 - by1);
    return inter / (area_a + area_b - inter);
}

__global__ __launch_bounds__(256) void yolo_loss_fused(const float* __restrict__ pred,
                                                       const float* __restrict__ targ,
                                                       float* __restrict__ out,
                                                       unsigned int* __restrict__ counter,
                                                       float* __restrict__ partial) {
    __shared__ float sp[CELLS_PER_BLOCK * CCH];   // 30720 B
    __shared__ float st[CELLS_PER_BLOCK * CCH];   // 30720 B

    const int tid = threadIdx.x;
    const int bid = blockIdx.x;
    const int block_cell0 = bid * CELLS_PER_BLOCK;

    // ---- Stage: issue ALL global loads first (max MLP), then write LDS ----
    // 256 cells * 30 floats = 1920 float4 per array; 7.5 per thread.
    const float4* p4 = (const float4*)(pred + (size_t)block_cell0 * CCH);
    const float4* t4 = (const float4*)(targ + (size_t)block_cell0 * CCH);
    float4* sp4 = (float4*)sp;
    float4* st4 = (float4*)st;

    float4 rp[8], rt[8];
#pragma unroll
    for (int j = 0; j < 7; ++j) { rp[j] = p4[tid + 256 * j]; rt[j] = t4[tid + 256 * j]; }
    const bool extra = tid < 128;
    if (extra) { rp[7] = p4[tid + 1792]; rt[7] = t4[tid + 1792]; }
#pragma unroll
    for (int j = 0; j < 7; ++j) { sp4[tid + 256 * j] = rp[j]; st4[tid + 256 * j] = rt[j]; }
    if (extra) { sp4[tid + 1792] = rp[7]; st4[tid + 1792] = rt[7]; }
    __syncthreads();

    // ---- Compute: one cell per thread ----
    const float* p = sp + tid * CCH;
    const float* t = st + tid * CCH;
    const int cell = block_cell0 + tid;
    const int xy = cell % (S7 * S7);
    const float fx = (float)(xy % S7);
    const float fy = (float)(xy / S7);
    const float ratio = 1.0f / 7.0f;

    float px1 = p[0], py1 = p[1], pw1 = p[2], ph1 = p[3], pc1 = p[4];
    float px2 = p[5], py2 = p[6], pw2 = p[7], ph2 = p[8], pc2 = p[9];
    float tx = t[0], ty = t[1], tw = t[2], th = t[3], tc = t[4];
    bool obj = tc > 0.0f;

    float tcx = (tx + fx) * ratio, tcy = (ty + fy) * ratio;
    float iou1 = iou_cxcywh((px1 + fx) * ratio, (py1 + fy) * ratio, pw1, ph1,
                            tcx, tcy, tw, th);
    float iou2 = iou_cxcywh((px2 + fx) * ratio, (py2 + fy) * ratio, pw2, ph2,
                            tcx, tcy, tw, th);
    bool resp = iou1 > iou2;

    float cls = 0.0f;
#pragma unroll
    for (int k = 10; k < 30; ++k) {
        float d = p[k] - t[k];
        cls += d * d;
    }

    float loss;
    if (obj) {
        float sx, sy, sw, sh, sc, siou;
        if (resp) { sx = px1; sy = py1; sw = pw1; sh = ph1; sc = pc1; siou = iou1; }
        else      { sx = px2; sy = py2; sw = pw2; sh = ph2; sc = pc2; siou = iou2; }
        float dx = sx - tx, dy = sy - ty;
        float dw = sqrtf(fmaxf(sw, EPSV)) - sqrtf(fmaxf(tw, EPSV));
        float dh = sqrtf(fmaxf(sh, EPSV)) - sqrtf(fmaxf(th, EPSV));
        float dc = sc - siou;
        loss = 5.0f * (dx * dx + dy * dy + dw * dw + dh * dh) + dc * dc + cls;
    } else {
        loss = 0.5f * (pc1 * pc1 + pc2 * pc2);
    }

    // ---- Block reduction ----
    float v = loss;
#pragma unroll
    for (int off = 32; off > 0; off >>= 1) v += __shfl_down(v, off);

    __shared__ float red[4];
    __shared__ bool is_last;
    const int lane = tid & 63;
    const int wid = tid >> 6;
    if (lane == 0) red[wid] = v;
    __syncthreads();

    // ---- Publish partial; last-arriving block reduces all partials ----
    if (tid == 0) {
        float bsum = red[0] + red[1] + red[2] + red[3];
        // Agent-scope release store: visible across XCDs (ws lines may be
        // 0xAA-poisoned in other XCDs' L2 — atomics bypass/flush correctly).
        __hip_atomic_store(&partial[bid], bsum, __ATOMIC_RELEASE, __HIP_MEMORY_SCOPE_AGENT);
        unsigned int prev = __hip_atomic_fetch_add(counter, 1u, __ATOMIC_ACQ_REL,
                                                   __HIP_MEMORY_SCOPE_AGENT);
        is_last = (prev == (unsigned int)(N_BLOCKS - 1));
    }
    __syncthreads();

    if (is_last) {
        float s = 0.0f;
        for (int i = tid; i < N_BLOCKS; i += 256)
            s += __hip_atomic_load(&partial[i], __ATOMIC_RELAXED, __HIP_MEMORY_SCOPE_AGENT);
#pragma unroll
        for (int off = 32; off > 0; off >>= 1) s += __shfl_down(s, off);
        if (lane == 0) red[wid] = s;
        __syncthreads();
        if (tid == 0) out[0] = red[0] + red[1] + red[2] + red[3];
    }
}

extern "C" void kernel_launch(void* const* d_in, const int* in_sizes, int n_in,
                              void* d_out, int out_size, void* d_ws, size_t ws_size,
                              hipStream_t stream) {
    const float* predicts = (const float*)d_in[0];
    const float* targets  = (const float*)d_in[1];
    float* out = (float*)d_out;

    unsigned int* counter = (unsigned int*)d_ws;              // 4 B at offset 0
    float* partial = (float*)((char*)d_ws + 256);             // N_BLOCKS floats

    // Zero the arrival counter (ws is re-poisoned to 0xAA before every call).
    hipMemsetAsync(counter, 0, sizeof(unsigned int), stream);

    yolo_loss_fused<<<N_BLOCKS, 256, 0, stream>>>(predicts, targets, out, counter, partial);
}

// Round 3
// 141.591 us; speedup vs baseline: 1.8561x; 1.8561x over previous
//
#include <hip/hip_runtime.h>
#include <math.h>

// YOLOv1 loss: predicts/targets (8192, 7, 7, 30) fp32 -> scalar.
// Two-kernel deterministic reduction (round-2's fused agent-scope atomics
// caused per-block L2 writeback/invalidate storms: 181us kernel, 94MB
// WRITE_SIZE — reverted). Improvements vs round 1: register-first staging
// (all global loads in flight before LDS writes), 128-cell/128-thread
// blocks (30KB LDS -> 5 blocks/CU = 10 waves/CU).

#define S7 7
#define CCH 30
#define CELLS_PER_BLOCK 128
#define THREADS 128
#define N_CELLS (8192 * S7 * S7)             // 401408
#define N_BLOCKS (N_CELLS / CELLS_PER_BLOCK) // 3136 exactly
#define V4_PER_ARR (CELLS_PER_BLOCK * CCH / 4) // 960 float4 per array
#define EPSV 1e-6f

__device__ __forceinline__ float iou_cxcywh(float acx, float acy, float aw, float ah,
                                            float bcx, float bcy, float bw, float bh) {
    float ax1 = acx - aw * 0.5f, ax2 = acx + aw * 0.5f;
    float ay1 = acy - ah * 0.5f, ay2 = acy + ah * 0.5f;
    float bx1 = bcx - bw * 0.5f, bx2 = bcx + bw * 0.5f;
    float by1 = bcy - bh * 0.5f, by2 = bcy + bh * 0.5f;
    float iw = fmaxf(fminf(ax2, bx2) - fmaxf(ax1, bx1), 0.0f);
    float ih = fmaxf(fminf(ay2, by2) - fmaxf(ay1, by1), 0.0f);
    float inter = iw * ih;
    float area_a = (ax2 - ax1) * (ay2 - ay1);
    float area_b = (bx2 - bx1) * (by2 - by1);
    return inter / (area_a + area_b - inter);
}

__global__ __launch_bounds__(THREADS) void yolo_loss_partial(const float* __restrict__ pred,
                                                             const float* __restrict__ targ,
                                                             float* __restrict__ partial) {
    __shared__ float sp[CELLS_PER_BLOCK * CCH];   // 15360 B
    __shared__ float st[CELLS_PER_BLOCK * CCH];   // 15360 B

    const int tid = threadIdx.x;
    const int bid = blockIdx.x;
    const int block_cell0 = bid * CELLS_PER_BLOCK;

    // ---- Stage: issue ALL global loads first (max MLP), then write LDS ----
    // 960 float4 per array, 128 threads -> 7 each + 64 threads one extra.
    const float4* p4 = (const float4*)(pred + (size_t)block_cell0 * CCH);
    const float4* t4 = (const float4*)(targ + (size_t)block_cell0 * CCH);
    float4* sp4 = (float4*)sp;
    float4* st4 = (float4*)st;

    float4 rp[8], rt[8];
#pragma unroll
    for (int j = 0; j < 7; ++j) { rp[j] = p4[tid + THREADS * j]; rt[j] = t4[tid + THREADS * j]; }
    const bool extra = tid < (V4_PER_ARR - 7 * THREADS);   // tid < 64
    if (extra) { rp[7] = p4[tid + 7 * THREADS]; rt[7] = t4[tid + 7 * THREADS]; }
#pragma unroll
    for (int j = 0; j < 7; ++j) { sp4[tid + THREADS * j] = rp[j]; st4[tid + THREADS * j] = rt[j]; }
    if (extra) { sp4[tid + 7 * THREADS] = rp[7]; st4[tid + 7 * THREADS] = rt[7]; }
    __syncthreads();

    // ---- Compute: one cell per thread ----
    const float* p = sp + tid * CCH;
    const float* t = st + tid * CCH;
    const int cell = block_cell0 + tid;
    const int xy = cell % (S7 * S7);
    const float fx = (float)(xy % S7);
    const float fy = (float)(xy / S7);
    const float ratio = 1.0f / 7.0f;

    float px1 = p[0], py1 = p[1], pw1 = p[2], ph1 = p[3], pc1 = p[4];
    float px2 = p[5], py2 = p[6], pw2 = p[7], ph2 = p[8], pc2 = p[9];
    float tx = t[0], ty = t[1], tw = t[2], th = t[3], tc = t[4];
    bool obj = tc > 0.0f;

    float tcx = (tx + fx) * ratio, tcy = (ty + fy) * ratio;
    float iou1 = iou_cxcywh((px1 + fx) * ratio, (py1 + fy) * ratio, pw1, ph1,
                            tcx, tcy, tw, th);
    float iou2 = iou_cxcywh((px2 + fx) * ratio, (py2 + fy) * ratio, pw2, ph2,
                            tcx, tcy, tw, th);
    bool resp = iou1 > iou2;

    float cls = 0.0f;
#pragma unroll
    for (int k = 10; k < 30; ++k) {
        float d = p[k] - t[k];
        cls += d * d;
    }

    float loss;
    if (obj) {
        float sx, sy, sw, sh, sc, siou;
        if (resp) { sx = px1; sy = py1; sw = pw1; sh = ph1; sc = pc1; siou = iou1; }
        else      { sx = px2; sy = py2; sw = pw2; sh = ph2; sc = pc2; siou = iou2; }
        float dx = sx - tx, dy = sy - ty;
        float dw = sqrtf(fmaxf(sw, EPSV)) - sqrtf(fmaxf(tw, EPSV));
        float dh = sqrtf(fmaxf(sh, EPSV)) - sqrtf(fmaxf(th, EPSV));
        float dc = sc - siou;
        loss = 5.0f * (dx * dx + dy * dy + dw * dw + dh * dh) + dc * dc + cls;
    } else {
        loss = 0.5f * (pc1 * pc1 + pc2 * pc2);
    }

    // ---- Block reduction: wave shuffle + 2 wave partials ----
    float v = loss;
#pragma unroll
    for (int off = 32; off > 0; off >>= 1) v += __shfl_down(v, off);

    __shared__ float red[2];
    const int lane = tid & 63;
    const int wid = tid >> 6;
    if (lane == 0) red[wid] = v;
    __syncthreads();
    if (tid == 0) partial[bid] = red[0] + red[1];
}

__global__ __launch_bounds__(256) void yolo_loss_final(const float* __restrict__ partial,
                                                       float* __restrict__ out) {
    float v = 0.0f;
    for (int i = threadIdx.x; i < N_BLOCKS; i += 256) v += partial[i];
#pragma unroll
    for (int off = 32; off > 0; off >>= 1) v += __shfl_down(v, off);

    __shared__ float red[4];
    const int lane = threadIdx.x & 63;
    const int wid = threadIdx.x >> 6;
    if (lane == 0) red[wid] = v;
    __syncthreads();
    if (threadIdx.x == 0) out[0] = red[0] + red[1] + red[2] + red[3];
}

extern "C" void kernel_launch(void* const* d_in, const int* in_sizes, int n_in,
                              void* d_out, int out_size, void* d_ws, size_t ws_size,
                              hipStream_t stream) {
    const float* predicts = (const float*)d_in[0];
    const float* targets  = (const float*)d_in[1];
    float* out = (float*)d_out;
    float* partial = (float*)d_ws;   // N_BLOCKS floats = 12544 B

    yolo_loss_partial<<<N_BLOCKS, THREADS, 0, stream>>>(predicts, targets, partial);
    yolo_loss_final<<<1, 256, 0, stream>>>(partial, out);
}

// Round 4
// 120.614 us; speedup vs baseline: 2.1789x; 1.1739x over previous
//
#include <hip/hip_runtime.h>
#include <math.h>

// YOLOv1 loss: predicts/targets (8192, 7, 7, 30) fp32 -> scalar.
//
// Round-1 shape restored: 256 threads / 256 cells per block, 60KB LDS,
// interleaved float4 staging loop (measured implied ~32us — near the
// ~30us floor set by 96MB input read + ~96MB harness-restore writeback
// contention that lands in our window; WRITE_SIZE==input footprint proved
// the writeback is harness dirty-line drain, not ours).
//
// Round-3 regression (128-thr blocks, burst staging): 53us — reverted.
// Round-2 regression (acq_rel agent atomics, last-block reduce): 181us —
// the acquire/release fences forced per-block L2 maintenance. This round
// uses a single RELAXED agent-scope fp32 atomicAdd per block (no fences,
// native global_atomic_add_f32) to drop the second kernel launch.

#define S7 7
#define CCH 30
#define CELLS_PER_BLOCK 256
#define THREADS 256
#define N_CELLS (8192 * S7 * S7)             // 401408
#define N_BLOCKS (N_CELLS / CELLS_PER_BLOCK) // 1568 exactly
#define V4_PER_ARR (CELLS_PER_BLOCK * CCH / 4) // 1920 float4 per array
#define EPSV 1e-6f

__device__ __forceinline__ float iou_cxcywh(float acx, float acy, float aw, float ah,
                                            float bcx, float bcy, float bw, float bh) {
    float ax1 = acx - aw * 0.5f, ax2 = acx + aw * 0.5f;
    float ay1 = acy - ah * 0.5f, ay2 = acy + ah * 0.5f;
    float bx1 = bcx - bw * 0.5f, bx2 = bcx + bw * 0.5f;
    float by1 = bcy - bh * 0.5f, by2 = bcy + bh * 0.5f;
    float iw = fmaxf(fminf(ax2, bx2) - fmaxf(ax1, bx1), 0.0f);
    float ih = fmaxf(fminf(ay2, by2) - fmaxf(ay1, by1), 0.0f);
    float inter = iw * ih;
    float area_a = (ax2 - ax1) * (ay2 - ay1);
    float area_b = (bx2 - bx1) * (by2 - by1);
    return inter / (area_a + area_b - inter);
}

__global__ __launch_bounds__(THREADS) void yolo_loss_kernel(const float* __restrict__ pred,
                                                            const float* __restrict__ targ,
                                                            float* __restrict__ out) {
    __shared__ float sp[CELLS_PER_BLOCK * CCH];   // 30720 B
    __shared__ float st[CELLS_PER_BLOCK * CCH];   // 30720 B

    const int tid = threadIdx.x;
    const int bid = blockIdx.x;
    const int block_cell0 = bid * CELLS_PER_BLOCK;

    // ---- Stage: coalesced float4 loads into LDS (R1's interleaved loop) ----
    const float4* p4 = (const float4*)(pred + (size_t)block_cell0 * CCH);
    const float4* t4 = (const float4*)(targ + (size_t)block_cell0 * CCH);
    float4* sp4 = (float4*)sp;
    float4* st4 = (float4*)st;
#pragma unroll
    for (int k = tid; k < V4_PER_ARR; k += THREADS) {
        sp4[k] = p4[k];
        st4[k] = t4[k];
    }
    __syncthreads();

    // ---- Compute: one cell per thread ----
    const float* p = sp + tid * CCH;
    const float* t = st + tid * CCH;
    const int cell = block_cell0 + tid;
    const int xy = cell % (S7 * S7);
    const float fx = (float)(xy % S7);
    const float fy = (float)(xy / S7);
    const float ratio = 1.0f / 7.0f;

    float px1 = p[0], py1 = p[1], pw1 = p[2], ph1 = p[3], pc1 = p[4];
    float px2 = p[5], py2 = p[6], pw2 = p[7], ph2 = p[8], pc2 = p[9];
    float tx = t[0], ty = t[1], tw = t[2], th = t[3], tc = t[4];
    bool obj = tc > 0.0f;

    float tcx = (tx + fx) * ratio, tcy = (ty + fy) * ratio;
    float iou1 = iou_cxcywh((px1 + fx) * ratio, (py1 + fy) * ratio, pw1, ph1,
                            tcx, tcy, tw, th);
    float iou2 = iou_cxcywh((px2 + fx) * ratio, (py2 + fy) * ratio, pw2, ph2,
                            tcx, tcy, tw, th);
    bool resp = iou1 > iou2;

    float cls = 0.0f;
#pragma unroll
    for (int k = 10; k < 30; ++k) {
        float d = p[k] - t[k];
        cls += d * d;
    }

    float loss;
    if (obj) {
        float sx, sy, sw, sh, sc, siou;
        if (resp) { sx = px1; sy = py1; sw = pw1; sh = ph1; sc = pc1; siou = iou1; }
        else      { sx = px2; sy = py2; sw = pw2; sh = ph2; sc = pc2; siou = iou2; }
        float dx = sx - tx, dy = sy - ty;
        float dw = sqrtf(fmaxf(sw, EPSV)) - sqrtf(fmaxf(tw, EPSV));
        float dh = sqrtf(fmaxf(sh, EPSV)) - sqrtf(fmaxf(th, EPSV));
        float dc = sc - siou;
        loss = 5.0f * (dx * dx + dy * dy + dw * dw + dh * dh) + dc * dc + cls;
    } else {
        loss = 0.5f * (pc1 * pc1 + pc2 * pc2);
    }

    // ---- Block reduction: wave shuffle + 4 wave partials ----
    float v = loss;
#pragma unroll
    for (int off = 32; off > 0; off >>= 1) v += __shfl_down(v, off);

    __shared__ float red[4];
    const int lane = tid & 63;
    const int wid = tid >> 6;
    if (lane == 0) red[wid] = v;
    __syncthreads();

    // ---- One RELAXED fp32 atomicAdd per block (no fences, no flushes) ----
    if (tid == 0) {
        float bsum = red[0] + red[1] + red[2] + red[3];
        __hip_atomic_fetch_add(out, bsum, __ATOMIC_RELAXED, __HIP_MEMORY_SCOPE_AGENT);
    }
}

extern "C" void kernel_launch(void* const* d_in, const int* in_sizes, int n_in,
                              void* d_out, int out_size, void* d_ws, size_t ws_size,
                              hipStream_t stream) {
    const float* predicts = (const float*)d_in[0];
    const float* targets  = (const float*)d_in[1];
    float* out = (float*)d_out;

    // out is re-poisoned to 0xAA before every timed replay; zero it ourselves
    // (memsetAsync inside capture is legal — proven in round 2).
    hipMemsetAsync(out, 0, sizeof(float), stream);

    yolo_loss_kernel<<<N_BLOCKS, THREADS, 0, stream>>>(predicts, targets, out);
}